// Round 2
// baseline (18569.817 us; speedup 1.0000x reference)
//
#include <hip/hip_runtime.h>

// Graph-gated LSTM recurrence, persistent cooperative kernel (round 2).
// R1 post-mortem: 157KB static __shared__ -> cooperative launch silently failed
// (out stayed zero; absmax 1.27e-2 == |mean(ref)|). Fixes:
//  - A-rows live in VGPRs (s8v afrag[32] = 128 VGPR/lane, 4-way K-split/wave),
//    LDS down to ~44KB (< 64KB static limit).
//  - launch return code checked; fallback plain launch (grid 256 <= 256 CUs).
//  - X double-buffer + barrier in __device__ globals (no ws_size assumption).
//  - X stored mean-centered (bf16 of X - cen[j]); exact fp32 correction
//    S_A[m]*cen[j] added after MFMA -> kills 2048x-amplified rounding bias.

#define NN   4096
#define TT   365
#define FF   16
#define HH   20
#define G4   80
#define RPB  16     // nodes per block
#define NBLK 256
#define NTHR 256
#define XR   48     // padded X^T rows (40 used; pad rows stay zero)
#define KSPL 1024   // K-slice per wave (4 waves * 1024 = 4096)

typedef float f4 __attribute__((ext_vector_type(4)));
typedef short s8v __attribute__((ext_vector_type(8)));

__device__ __attribute__((aligned(16))) unsigned short g_X[2 * XR * NN]; // 768KB, zero-init
__device__ unsigned g_bar[2];

struct __align__(16) Smem {
  float WkT[G4][FF];              // lstm kernel, transposed
  float WrT[G4][HH];              // lstm recurrent, transposed
  float WghT[HH][HH]; float WgcT[HH][HH];
  float WhcT[HH][HH]; float WhpT[HH][HH];
  float WccT[HH][HH]; float WcpT[HH][HH];
  float Wout[HH];
  float bias[G4];
  float bgh[HH]; float bgc[HH]; float bhv[HH]; float bcv[HH];
  float bout; float pad0[3];
  float hprev[RPB][HH]; float cprev[RPB][HH];
  float hcur[RPB][HH];  float ccur[RPB][HH];
  float hg[RPB][HH];    float cg[RPB][HH];
  float cen[2 * HH];              // 0.5 * column-sum of Wgh/Wgc (X centering)
  float SA[RPB];                  // per-row sum of bf16(A) (fp32, exact-ish)
  float sAp[16][16];              // one-time partials for SA
  float part[4][3][16][17];       // per-wave MFMA partials [wave][tile][row][col]
};                                // total ~43.8 KB

__device__ inline float sigm(float x) { return 1.f / (1.f + __expf(-x)); }
__device__ inline float tanh_f(float x) { return 2.f / (1.f + __expf(-2.f * x)) - 1.f; }

__device__ inline unsigned short f2bf(float f) {   // RNE fp32->bf16
  unsigned u = __float_as_uint(f);
  u = u + 0x7FFFu + ((u >> 16) & 1u);
  return (unsigned short)(u >> 16);
}
__device__ inline float bf2f(unsigned short u) {
  return __uint_as_float(((unsigned)u) << 16);
}

__device__ inline void grid_barrier() {
  __syncthreads();                       // all block stores drained (vmcnt 0)
  if (threadIdx.x == 0) {
    __threadfence();                     // release: wb local L2 to coherence point
    unsigned g = __hip_atomic_load(&g_bar[1], __ATOMIC_RELAXED, __HIP_MEMORY_SCOPE_AGENT);
    unsigned a = __hip_atomic_fetch_add(&g_bar[0], 1u, __ATOMIC_ACQ_REL, __HIP_MEMORY_SCOPE_AGENT);
    if (a == (unsigned)(NBLK - 1)) {
      __hip_atomic_store(&g_bar[0], 0u, __ATOMIC_RELAXED, __HIP_MEMORY_SCOPE_AGENT);
      __hip_atomic_store(&g_bar[1], g + 1u, __ATOMIC_RELEASE, __HIP_MEMORY_SCOPE_AGENT);
    } else {
      while (__hip_atomic_load(&g_bar[1], __ATOMIC_ACQUIRE, __HIP_MEMORY_SCOPE_AGENT) == g)
        __builtin_amdgcn_s_sleep(1);
    }
    __threadfence();                     // acquire: invalidate L1 + local L2
  }
  __syncthreads();
}

// LSTM cell for the block's 16 nodes at time t. hprev/cprev -> hcur/ccur.
// stride must be a multiple of 16 so n = lid&15 is loop-invariant.
__device__ inline void lstm_cells(Smem& sm, const float* __restrict__ inputs,
                                  int nb0, int t, int lid, int stride) {
  const int n = lid & 15;
  const float* xr = inputs + ((size_t)(nb0 + n) * TT + t) * FF;
  const f4 x0 = *(const f4*)(xr);
  const f4 x1 = *(const f4*)(xr + 4);
  const f4 x2 = *(const f4*)(xr + 8);
  const f4 x3 = *(const f4*)(xr + 12);
  const f4* hpr = (const f4*)sm.hprev[n];
  const f4 hp0 = hpr[0], hp1 = hpr[1], hp2 = hpr[2], hp3 = hpr[3], hp4 = hpr[4];
  for (int idx = lid; idx < RPB * HH; idx += stride) {
    const int h = idx >> 4;
    float z[4];
#pragma unroll
    for (int g = 0; g < 4; g++) {
      const int col = g * HH + h;
      const f4* wk = (const f4*)sm.WkT[col];
      f4 acc = x0 * wk[0] + x1 * wk[1] + x2 * wk[2] + x3 * wk[3];
      const f4* wr = (const f4*)sm.WrT[col];
      acc += hp0 * wr[0] + hp1 * wr[1] + hp2 * wr[2] + hp3 * wr[3] + hp4 * wr[4];
      z[g] = sm.bias[col] + acc[0] + acc[1] + acc[2] + acc[3];
    }
    const float co = sm.cprev[n][h];
    const float cn = sigm(z[1]) * co + sigm(z[0]) * tanh_f(z[2]);
    const float hn = sigm(z[3]) * tanh_f(cn);
    sm.hcur[n][h] = hn;
    sm.ccur[n][h] = cn;
  }
}

// X^T[j][node] (bf16, centered) for the next step, from current hprev/cprev.
__device__ inline void produce_X(Smem& sm, int wb, int nb0, int tid) {
  for (int idx = tid; idx < RPB * 2 * HH; idx += NTHR) {
    const int n = idx & 15, j = idx >> 4;   // j in [0,40)
    const f4* st; const f4* w; float b0;
    if (j < HH) { st = (const f4*)sm.hprev[n]; w = (const f4*)sm.WghT[j]; b0 = sm.bgh[j]; }
    else        { st = (const f4*)sm.cprev[n]; w = (const f4*)sm.WgcT[j - HH]; b0 = sm.bgc[j - HH]; }
    f4 acc = st[0]*w[0] + st[1]*w[1] + st[2]*w[2] + st[3]*w[3] + st[4]*w[4];
    const float v = b0 + acc[0] + acc[1] + acc[2] + acc[3];
    g_X[((size_t)(wb * XR + j) << 12) + (unsigned)(nb0 + n)] = f2bf(v - sm.cen[j]);
  }
}

__global__ void bar_init() {
  if (threadIdx.x == 0) { g_bar[0] = 0u; g_bar[1] = 0u; }
}

__global__ void __launch_bounds__(NTHR, 1)
gg_kernel(const float* __restrict__ inputs, const float* __restrict__ Ag,
          const float* __restrict__ Wk, const float* __restrict__ Wr, const float* __restrict__ bls,
          const float* __restrict__ Wgh, const float* __restrict__ bgh,
          const float* __restrict__ Wgc, const float* __restrict__ bgc,
          const float* __restrict__ Whc, const float* __restrict__ Whp, const float* __restrict__ bh,
          const float* __restrict__ Wcc, const float* __restrict__ Wcp, const float* __restrict__ bc,
          const float* __restrict__ Wo, const float* __restrict__ bo,
          float* __restrict__ out) {
  __shared__ Smem sm;
  const int tid  = threadIdx.x;
  const int nb0  = blockIdx.x * RPB;
  const int lane = tid & 63;
  const int wv   = tid >> 6;
  const int li   = lane & 15;
  const int quad = lane >> 4;

  // ---- one-time: weights (transposed) into LDS ----
  for (int i = tid; i < FF * G4; i += NTHR) sm.WkT[i % G4][i / G4] = Wk[i];
  for (int i = tid; i < HH * G4; i += NTHR) sm.WrT[i % G4][i / G4] = Wr[i];
  for (int i = tid; i < HH * HH; i += NTHR) {
    const int r = i / HH, c = i % HH;
    sm.WghT[c][r] = Wgh[i]; sm.WgcT[c][r] = Wgc[i];
    sm.WhcT[c][r] = Whc[i]; sm.WhpT[c][r] = Whp[i];
    sm.WccT[c][r] = Wcc[i]; sm.WcpT[c][r] = Wcp[i];
  }
  for (int i = tid; i < G4; i += NTHR) sm.bias[i] = bls[i];
  if (tid < HH) { sm.bgh[tid] = bgh[tid]; sm.bgc[tid] = bgc[tid]; sm.bhv[tid] = bh[tid]; sm.bcv[tid] = bc[tid]; sm.Wout[tid] = Wo[tid]; }
  if (tid == 0) sm.bout = bo[0];
  for (int i = tid; i < RPB * HH; i += NTHR) { (&sm.hprev[0][0])[i] = 0.f; (&sm.cprev[0][0])[i] = 0.f; }
  __syncthreads();

  // cen[j] = b[j] + 0.5 * column-sum(W): X values cluster here (states ~ sigmoid ~ 0.5)
  if (tid < 2 * HH) {
    const int j = tid;
    float s = 0.f;
    if (j < HH) { for (int h = 0; h < HH; h++) s += sm.WghT[j][h]; s = sm.bgh[j] + 0.5f * s; }
    else        { for (int h = 0; h < HH; h++) s += sm.WgcT[j - HH][h]; s = sm.bgc[j - HH] + 0.5f * s; }
    sm.cen[j] = s;
  }

  // ---- one-time: A rows -> VGPR fragments (bf16), plus row sums of bf16(A) ----
  s8v afrag[32];
  {
    const float* Arow = Ag + (size_t)(nb0 + li) * NN + (size_t)(wv * KSPL + quad * 8);
    double ds = 0.0;
#pragma unroll
    for (int i = 0; i < 32; i++) {
      const f4 v0 = *(const f4*)(Arow + i * 32);
      const f4 v1 = *(const f4*)(Arow + i * 32 + 4);
      s8v tb;
      tb[0] = (short)f2bf(v0[0]); tb[1] = (short)f2bf(v0[1]);
      tb[2] = (short)f2bf(v0[2]); tb[3] = (short)f2bf(v0[3]);
      tb[4] = (short)f2bf(v1[0]); tb[5] = (short)f2bf(v1[1]);
      tb[6] = (short)f2bf(v1[2]); tb[7] = (short)f2bf(v1[3]);
      afrag[i] = tb;
#pragma unroll
      for (int e = 0; e < 8; e++) ds += (double)bf2f((unsigned short)tb[e]);
    }
    sm.sAp[wv * 4 + quad][li] = (float)ds;
  }
  __syncthreads();
  if (tid < RPB) {
    float s = 0.f;
#pragma unroll
    for (int g = 0; g < 16; g++) s += sm.sAp[g][tid];
    sm.SA[tid] = s;
  }

  // ---- warm phase: T LSTM steps, block-local ----
  for (int t = 0; t < TT; t++) {
    __syncthreads();
    lstm_cells(sm, inputs, nb0, t, tid, NTHR);
    __syncthreads();
    for (int i = tid; i < RPB * HH; i += NTHR) {
      (&sm.hprev[0][0])[i] = (&sm.hcur[0][0])[i];
      (&sm.cprev[0][0])[i] = (&sm.ccur[0][0])[i];
    }
  }
  __syncthreads();
  produce_X(sm, 1, nb0, tid);            // X_1 from (h0,c0)
  grid_barrier();

  // ---- main recurrence: t = 1..364, one grid barrier per step ----
  for (int t = 1; t < TT; t++) {
    const int rb = t & 1;
    // MFMA partials: this wave's K-slice, 3 col-tiles of 16
    const unsigned short* Xt = g_X + ((size_t)(rb * XR) << 12) + (size_t)(wv * KSPL + quad * 8);
#pragma unroll
    for (int c = 0; c < 3; c++) {
      const unsigned short* Xrow = Xt + ((size_t)(c * 16 + li) << 12);
      f4 a0 = {0.f, 0.f, 0.f, 0.f}, a1 = a0, a2 = a0, a3 = a0;
#pragma unroll
      for (int i = 0; i < 32; i += 4) {
        a0 = __builtin_amdgcn_mfma_f32_16x16x32_bf16(afrag[i + 0], *(const s8v*)(Xrow + (i + 0) * 32), a0, 0, 0, 0);
        a1 = __builtin_amdgcn_mfma_f32_16x16x32_bf16(afrag[i + 1], *(const s8v*)(Xrow + (i + 1) * 32), a1, 0, 0, 0);
        a2 = __builtin_amdgcn_mfma_f32_16x16x32_bf16(afrag[i + 2], *(const s8v*)(Xrow + (i + 2) * 32), a2, 0, 0, 0);
        a3 = __builtin_amdgcn_mfma_f32_16x16x32_bf16(afrag[i + 3], *(const s8v*)(Xrow + (i + 3) * 32), a3, 0, 0, 0);
      }
      const f4 ac = (a0 + a1) + (a2 + a3);
#pragma unroll
      for (int r = 0; r < 4; r++) sm.part[wv][c][quad * 4 + r][li] = ac[r];
    }
    __syncthreads();

    // waves 0-2: cross-wave reduce + centering correction + tanh -> hg/cg
    // wave 3: LSTM cell
    if (tid < 192) {
#pragma unroll
      for (int p = 0; p < 4; p++) {
        const int idx = tid + 192 * p;
        const int c = idx >> 8, rc = idx & 255, r = rc >> 4, col = rc & 15;
        const int gc = c * 16 + col;
        if (gc < 2 * HH) {
          const float s = sm.part[0][c][r][col] + sm.part[1][c][r][col]
                        + sm.part[2][c][r][col] + sm.part[3][c][r][col];
          const float v = s + sm.SA[r] * sm.cen[gc];
          const float tv = tanh_f(v);
          if (gc < HH) sm.hg[r][gc] = tv; else sm.cg[r][gc - HH] = tv;
        }
      }
    } else {
      lstm_cells(sm, inputs, nb0, t, tid - 192, 64);
    }
    __syncthreads();

    // update stage: h_upd = sig(hcur@Whc + hg@Whp + bh); c_upd likewise
    for (int idx = tid; idx < 2 * RPB * HH; idx += NTHR) {
      int q = idx; int cpath = 0;
      if (q >= RPB * HH) { q -= RPB * HH; cpath = 1; }
      const int n = q & 15, h = q >> 4;
      const f4* cur = (const f4*)(cpath ? sm.ccur[n] : sm.hcur[n]);
      const f4* gr2 = (const f4*)(cpath ? sm.cg[n] : sm.hg[n]);
      const f4* w1  = (const f4*)(cpath ? sm.WccT[h] : sm.WhcT[h]);
      const f4* w2  = (const f4*)(cpath ? sm.WcpT[h] : sm.WhpT[h]);
      f4 acc = cur[0]*w1[0] + cur[1]*w1[1] + cur[2]*w1[2] + cur[3]*w1[3] + cur[4]*w1[4];
      acc   += gr2[0]*w2[0] + gr2[1]*w2[1] + gr2[2]*w2[2] + gr2[3]*w2[3] + gr2[4]*w2[4];
      const float b0 = cpath ? sm.bcv[h] : sm.bhv[h];
      const float v = sigm(b0 + acc[0] + acc[1] + acc[2] + acc[3]);
      if (cpath) sm.cprev[n][h] = v; else sm.hprev[n][h] = v;
    }
    __syncthreads();

    produce_X(sm, (t + 1) & 1, nb0, tid);          // X for step t+1
    if (tid < RPB) {                               // out[t-1, node] = h_upd @ W_out + b
      float acc = sm.bout;
#pragma unroll
      for (int h2 = 0; h2 < HH; h2++) acc += sm.hprev[tid][h2] * sm.Wout[h2];
      out[(size_t)(t - 1) * NN + nb0 + tid] = acc;
    }
    grid_barrier();
  }
}

extern "C" void kernel_launch(void* const* d_in, const int* in_sizes, int n_in,
                              void* d_out, int out_size, void* d_ws, size_t ws_size,
                              hipStream_t stream) {
  (void)in_sizes; (void)n_in; (void)out_size; (void)d_ws; (void)ws_size;
  const float* inputs = (const float*)d_in[0];
  const float* Ag     = (const float*)d_in[1];
  const float* Wk     = (const float*)d_in[2];
  const float* Wr     = (const float*)d_in[3];
  const float* bls    = (const float*)d_in[4];
  const float* Wgh    = (const float*)d_in[5];
  const float* bgh    = (const float*)d_in[6];
  const float* Wgc    = (const float*)d_in[7];
  const float* bgc    = (const float*)d_in[8];
  const float* Whc    = (const float*)d_in[9];
  const float* Whp    = (const float*)d_in[10];
  const float* bh     = (const float*)d_in[11];
  const float* Wcc    = (const float*)d_in[12];
  const float* Wcp    = (const float*)d_in[13];
  const float* bc     = (const float*)d_in[14];
  const float* Wo     = (const float*)d_in[15];
  const float* bo     = (const float*)d_in[16];
  float* out = (float*)d_out;

  bar_init<<<dim3(1), dim3(64), 0, stream>>>();

  void* args[] = { (void*)&inputs, (void*)&Ag, (void*)&Wk, (void*)&Wr, (void*)&bls,
                   (void*)&Wgh, (void*)&bgh, (void*)&Wgc, (void*)&bgc,
                   (void*)&Whc, (void*)&Whp, (void*)&bh,
                   (void*)&Wcc, (void*)&Wcp, (void*)&bc,
                   (void*)&Wo, (void*)&bo, (void*)&out };
  hipError_t err = hipLaunchCooperativeKernel((void*)gg_kernel, dim3(NBLK), dim3(NTHR),
                                              args, 0, stream);
  if (err != hipSuccess) {
    (void)hipGetLastError();   // clear; fall back to plain launch (256 blocks <= 256 CUs)
    gg_kernel<<<dim3(NBLK), dim3(NTHR), 0, stream>>>(inputs, Ag, Wk, Wr, bls,
                                                     Wgh, bgh, Wgc, bgc,
                                                     Whc, Whp, bh, Wcc, Wcp, bc,
                                                     Wo, bo, out);
  }
}

// Round 3
// 11036.353 us; speedup vs baseline: 1.6826x; 1.6826x over previous
//
#include <hip/hip_runtime.h>

// Graph-gated LSTM recurrence, persistent cooperative kernel (round 3).
// R2 post-mortem: passed, 18.0ms; 49.5us/step while work/step is ~3.5us.
// Diagnosis: 256-way atomic fetch_add on ONE cacheline serializes at the
// coherence point (~470cyc each = ~50us/step). Fixes this round:
//  - Flag-array barrier: per-block arrival slot (128B apart, concurrent
//    relaxed stores), block 0 polls all 256 slots with 256 threads, then one
//    release word everyone spins on. No atomic RMW anywhere.
//  - Split arrive/wait: next step's (block-local) LSTM cell computed between
//    publishing X and waiting, hiding part of the barrier latency.
//  - Warm phase: x(t+1) prefetched into regs while computing step t.
//  - Dead barrier after final step removed.

#define NN   4096
#define TT   365
#define FF   16
#define HH   20
#define G4   80
#define RPB  16     // nodes per block
#define NBLK 256
#define NTHR 256
#define XR   48     // padded X^T rows (40 used; pad rows stay zero)
#define KSPL 1024   // K-slice per wave (4 waves * 1024 = 4096)
#define SLOTS 32    // uints per arrival slot (128 B)

static_assert(NBLK == NTHR, "block0 poll maps one slot per thread");

typedef float f4 __attribute__((ext_vector_type(4)));
typedef short s8v __attribute__((ext_vector_type(8)));

__device__ __attribute__((aligned(16))) unsigned short g_X[2 * XR * NN]; // 768KB
__device__ unsigned g_arrive[NBLK * SLOTS];   // one 128B slot per block
__device__ unsigned g_release;

struct __align__(16) Smem {
  float WkT[G4][FF];              // lstm kernel, transposed
  float WrT[G4][HH];              // lstm recurrent, transposed
  float WghT[HH][HH]; float WgcT[HH][HH];
  float WhcT[HH][HH]; float WhpT[HH][HH];
  float WccT[HH][HH]; float WcpT[HH][HH];
  float Wout[HH];
  float bias[G4];
  float bgh[HH]; float bgc[HH]; float bhv[HH]; float bcv[HH];
  float bout; float pad0[3];
  float hprev[RPB][HH]; float cprev[RPB][HH];
  float hcur[RPB][HH];  float ccur[RPB][HH];
  float hg[RPB][HH];    float cg[RPB][HH];
  float cen[2 * HH];              // X centering values
  float SA[RPB];                  // per-row sum of bf16(A)
  float sAp[16][16];
  float part[4][3][16][17];       // per-wave MFMA partials
};                                // ~43.8 KB

__device__ inline float sigm(float x) { return 1.f / (1.f + __expf(-x)); }
__device__ inline float tanh_f(float x) { return 2.f / (1.f + __expf(-2.f * x)) - 1.f; }

__device__ inline unsigned short f2bf(float f) {   // RNE fp32->bf16
  unsigned u = __float_as_uint(f);
  u = u + 0x7FFFu + ((u >> 16) & 1u);
  return (unsigned short)(u >> 16);
}
__device__ inline float bf2f(unsigned short u) {
  return __uint_as_float(((unsigned)u) << 16);
}

// ---- flag-array grid barrier (no atomic RMW) ----
__device__ inline void gb_arrive(unsigned gen) {
  __syncthreads();                      // all block stores issued+drained
  if (threadIdx.x == 0) {
    __threadfence();                    // release: publish X to coherence point
    __hip_atomic_store(&g_arrive[blockIdx.x * SLOTS], gen,
                       __ATOMIC_RELAXED, __HIP_MEMORY_SCOPE_AGENT);
  }
}

__device__ inline void gb_wait(unsigned gen) {
  if (blockIdx.x == 0) {
    // 256 threads poll 256 slots concurrently
    while (__hip_atomic_load(&g_arrive[threadIdx.x * SLOTS],
                             __ATOMIC_RELAXED, __HIP_MEMORY_SCOPE_AGENT) < gen)
      __builtin_amdgcn_s_sleep(1);
    __syncthreads();
    if (threadIdx.x == 0) {
      __hip_atomic_store(&g_release, gen, __ATOMIC_RELEASE, __HIP_MEMORY_SCOPE_AGENT);
      __threadfence();                  // acquire for our own X reads
    }
  } else {
    if (threadIdx.x == 0) {
      while (__hip_atomic_load(&g_release, __ATOMIC_RELAXED,
                               __HIP_MEMORY_SCOPE_AGENT) < gen)
        __builtin_amdgcn_s_sleep(1);
      __threadfence();                  // acquire: invalidate stale cached X
    }
  }
  __syncthreads();
}

__device__ inline void load_x(const float* __restrict__ inputs, int nb0, int t,
                              int tid, f4* x) {
  const float* xr = inputs + ((size_t)(nb0 + (tid & 15)) * TT + t) * FF;
  x[0] = *(const f4*)(xr);
  x[1] = *(const f4*)(xr + 4);
  x[2] = *(const f4*)(xr + 8);
  x[3] = *(const f4*)(xr + 12);
}

// LSTM cell for the block's 16 nodes; x pre-loaded for node tid&15.
// All NTHR threads participate (items idx, idx+256).
__device__ inline void lstm_cells_x(Smem& sm, const f4* x, int tid) {
  const int n = tid & 15;
  const f4* hpr = (const f4*)sm.hprev[n];
  const f4 hp0 = hpr[0], hp1 = hpr[1], hp2 = hpr[2], hp3 = hpr[3], hp4 = hpr[4];
  for (int idx = tid; idx < RPB * HH; idx += NTHR) {
    const int h = idx >> 4;
    float z[4];
#pragma unroll
    for (int g = 0; g < 4; g++) {
      const int col = g * HH + h;
      const f4* wk = (const f4*)sm.WkT[col];
      f4 acc = x[0] * wk[0] + x[1] * wk[1] + x[2] * wk[2] + x[3] * wk[3];
      const f4* wr = (const f4*)sm.WrT[col];
      acc += hp0 * wr[0] + hp1 * wr[1] + hp2 * wr[2] + hp3 * wr[3] + hp4 * wr[4];
      z[g] = sm.bias[col] + acc[0] + acc[1] + acc[2] + acc[3];
    }
    const float co = sm.cprev[n][h];
    const float cn = sigm(z[1]) * co + sigm(z[0]) * tanh_f(z[2]);
    const float hn = sigm(z[3]) * tanh_f(cn);
    sm.hcur[n][h] = hn;
    sm.ccur[n][h] = cn;
  }
}

// X^T[j][node] (bf16, centered) for the next step, from current hprev/cprev.
__device__ inline void produce_X(Smem& sm, int wb, int nb0, int tid) {
  for (int idx = tid; idx < RPB * 2 * HH; idx += NTHR) {
    const int n = idx & 15, j = idx >> 4;   // j in [0,40)
    const f4* st; const f4* w; float b0;
    if (j < HH) { st = (const f4*)sm.hprev[n]; w = (const f4*)sm.WghT[j]; b0 = sm.bgh[j]; }
    else        { st = (const f4*)sm.cprev[n]; w = (const f4*)sm.WgcT[j - HH]; b0 = sm.bgc[j - HH]; }
    f4 acc = st[0]*w[0] + st[1]*w[1] + st[2]*w[2] + st[3]*w[3] + st[4]*w[4];
    const float v = b0 + acc[0] + acc[1] + acc[2] + acc[3];
    g_X[((size_t)(wb * XR + j) << 12) + (unsigned)(nb0 + n)] = f2bf(v - sm.cen[j]);
  }
}

__global__ void bar_init() {
  g_arrive[threadIdx.x * SLOTS] = 0u;
  if (threadIdx.x == 0) g_release = 0u;
}

__global__ void __launch_bounds__(NTHR, 1)
gg_kernel(const float* __restrict__ inputs, const float* __restrict__ Ag,
          const float* __restrict__ Wk, const float* __restrict__ Wr, const float* __restrict__ bls,
          const float* __restrict__ Wgh, const float* __restrict__ bgh,
          const float* __restrict__ Wgc, const float* __restrict__ bgc,
          const float* __restrict__ Whc, const float* __restrict__ Whp, const float* __restrict__ bh,
          const float* __restrict__ Wcc, const float* __restrict__ Wcp, const float* __restrict__ bc,
          const float* __restrict__ Wo, const float* __restrict__ bo,
          float* __restrict__ out) {
  __shared__ Smem sm;
  const int tid  = threadIdx.x;
  const int nb0  = blockIdx.x * RPB;
  const int lane = tid & 63;
  const int wv   = tid >> 6;
  const int li   = lane & 15;
  const int quad = lane >> 4;

  // ---- one-time: weights (transposed) into LDS ----
  for (int i = tid; i < FF * G4; i += NTHR) sm.WkT[i % G4][i / G4] = Wk[i];
  for (int i = tid; i < HH * G4; i += NTHR) sm.WrT[i % G4][i / G4] = Wr[i];
  for (int i = tid; i < HH * HH; i += NTHR) {
    const int r = i / HH, c = i % HH;
    sm.WghT[c][r] = Wgh[i]; sm.WgcT[c][r] = Wgc[i];
    sm.WhcT[c][r] = Whc[i]; sm.WhpT[c][r] = Whp[i];
    sm.WccT[c][r] = Wcc[i]; sm.WcpT[c][r] = Wcp[i];
  }
  for (int i = tid; i < G4; i += NTHR) sm.bias[i] = bls[i];
  if (tid < HH) { sm.bgh[tid] = bgh[tid]; sm.bgc[tid] = bgc[tid]; sm.bhv[tid] = bh[tid]; sm.bcv[tid] = bc[tid]; sm.Wout[tid] = Wo[tid]; }
  if (tid == 0) sm.bout = bo[0];
  for (int i = tid; i < RPB * HH; i += NTHR) { (&sm.hprev[0][0])[i] = 0.f; (&sm.cprev[0][0])[i] = 0.f; }
  __syncthreads();

  // cen[j] = b[j] + 0.5 * column-sum(W): X values cluster here
  if (tid < 2 * HH) {
    const int j = tid;
    float s = 0.f;
    if (j < HH) { for (int h = 0; h < HH; h++) s += sm.WghT[j][h]; s = sm.bgh[j] + 0.5f * s; }
    else        { for (int h = 0; h < HH; h++) s += sm.WgcT[j - HH][h]; s = sm.bgc[j - HH] + 0.5f * s; }
    sm.cen[j] = s;
  }

  // ---- one-time: A rows -> VGPR fragments (bf16) + row sums of bf16(A) ----
  s8v afrag[32];
  {
    const float* Arow = Ag + (size_t)(nb0 + li) * NN + (size_t)(wv * KSPL + quad * 8);
    double ds = 0.0;
#pragma unroll
    for (int i = 0; i < 32; i++) {
      const f4 v0 = *(const f4*)(Arow + i * 32);
      const f4 v1 = *(const f4*)(Arow + i * 32 + 4);
      s8v tb;
      tb[0] = (short)f2bf(v0[0]); tb[1] = (short)f2bf(v0[1]);
      tb[2] = (short)f2bf(v0[2]); tb[3] = (short)f2bf(v0[3]);
      tb[4] = (short)f2bf(v1[0]); tb[5] = (short)f2bf(v1[1]);
      tb[6] = (short)f2bf(v1[2]); tb[7] = (short)f2bf(v1[3]);
      afrag[i] = tb;
#pragma unroll
      for (int e = 0; e < 8; e++) ds += (double)bf2f((unsigned short)tb[e]);
    }
    sm.sAp[wv * 4 + quad][li] = (float)ds;
  }
  __syncthreads();
  if (tid < RPB) {
    float s = 0.f;
#pragma unroll
    for (int g = 0; g < 16; g++) s += sm.sAp[g][tid];
    sm.SA[tid] = s;
  }

  // ---- warm phase: T LSTM steps, block-local, x prefetched one step ahead ----
  f4 xa[4], xb[4];
  load_x(inputs, nb0, 0, tid, xa);
  for (int t = 0; t < TT; t++) {
    if (t + 1 < TT) load_x(inputs, nb0, t + 1, tid, xb);
    __syncthreads();
    lstm_cells_x(sm, xa, tid);
    __syncthreads();
    for (int i = tid; i < RPB * HH; i += NTHR) {
      (&sm.hprev[0][0])[i] = (&sm.hcur[0][0])[i];
      (&sm.cprev[0][0])[i] = (&sm.ccur[0][0])[i];
    }
    xa[0] = xb[0]; xa[1] = xb[1]; xa[2] = xb[2]; xa[3] = xb[3];
  }
  __syncthreads();

  // prologue: publish X_1, then LSTM(t=1) in the arrive/wait gap
  produce_X(sm, 1, nb0, tid);
  gb_arrive(1u);
  load_x(inputs, nb0, 1, tid, xa);
  lstm_cells_x(sm, xa, tid);
  gb_wait(1u);

  // ---- main recurrence: t = 1..364 ----
  for (int t = 1; t < TT; t++) {
    const int rb = t & 1;
    // MFMA partials: this wave's K-slice, 3 col-tiles of 16
    const unsigned short* Xt = g_X + ((size_t)(rb * XR) << 12) + (size_t)(wv * KSPL + quad * 8);
#pragma unroll
    for (int c = 0; c < 3; c++) {
      const unsigned short* Xrow = Xt + ((size_t)(c * 16 + li) << 12);
      f4 a0 = {0.f, 0.f, 0.f, 0.f}, a1 = a0, a2 = a0, a3 = a0;
#pragma unroll
      for (int i = 0; i < 32; i += 4) {
        a0 = __builtin_amdgcn_mfma_f32_16x16x32_bf16(afrag[i + 0], *(const s8v*)(Xrow + (i + 0) * 32), a0, 0, 0, 0);
        a1 = __builtin_amdgcn_mfma_f32_16x16x32_bf16(afrag[i + 1], *(const s8v*)(Xrow + (i + 1) * 32), a1, 0, 0, 0);
        a2 = __builtin_amdgcn_mfma_f32_16x16x32_bf16(afrag[i + 2], *(const s8v*)(Xrow + (i + 2) * 32), a2, 0, 0, 0);
        a3 = __builtin_amdgcn_mfma_f32_16x16x32_bf16(afrag[i + 3], *(const s8v*)(Xrow + (i + 3) * 32), a3, 0, 0, 0);
      }
      const f4 ac = (a0 + a1) + (a2 + a3);
#pragma unroll
      for (int r = 0; r < 4; r++) sm.part[wv][c][quad * 4 + r][li] = ac[r];
    }
    __syncthreads();

    // cross-wave reduce + centering correction + tanh -> hg/cg (all threads)
#pragma unroll
    for (int p = 0; p < 3; p++) {
      const int idx = tid + NTHR * p;
      const int c = idx >> 8, rc = idx & 255, r = rc >> 4, col = rc & 15;
      const int gc = c * 16 + col;
      if (gc < 2 * HH) {
        const float s = sm.part[0][c][r][col] + sm.part[1][c][r][col]
                      + sm.part[2][c][r][col] + sm.part[3][c][r][col];
        const float v = s + sm.SA[r] * sm.cen[gc];
        const float tv = tanh_f(v);
        if (gc < HH) sm.hg[r][gc] = tv; else sm.cg[r][gc - HH] = tv;
      }
    }
    __syncthreads();

    // update stage: h_upd = sig(hcur@Whc + hg@Whp + bh); c_upd likewise
    for (int idx = tid; idx < 2 * RPB * HH; idx += NTHR) {
      int q = idx; int cpath = 0;
      if (q >= RPB * HH) { q -= RPB * HH; cpath = 1; }
      const int n = q & 15, h = q >> 4;
      const f4* cur = (const f4*)(cpath ? sm.ccur[n] : sm.hcur[n]);
      const f4* gr2 = (const f4*)(cpath ? sm.cg[n] : sm.hg[n]);
      const f4* w1  = (const f4*)(cpath ? sm.WccT[h] : sm.WhcT[h]);
      const f4* w2  = (const f4*)(cpath ? sm.WcpT[h] : sm.WhpT[h]);
      f4 acc = cur[0]*w1[0] + cur[1]*w1[1] + cur[2]*w1[2] + cur[3]*w1[3] + cur[4]*w1[4];
      acc   += gr2[0]*w2[0] + gr2[1]*w2[1] + gr2[2]*w2[2] + gr2[3]*w2[3] + gr2[4]*w2[4];
      const float b0 = cpath ? sm.bcv[h] : sm.bhv[h];
      const float v = sigm(b0 + acc[0] + acc[1] + acc[2] + acc[3]);
      if (cpath) sm.cprev[n][h] = v; else sm.hprev[n][h] = v;
    }
    __syncthreads();

    if (tid < RPB) {                               // out[t-1, node] = h_upd @ W_out + b
      float acc = sm.bout;
#pragma unroll
      for (int h2 = 0; h2 < HH; h2++) acc += sm.hprev[tid][h2] * sm.Wout[h2];
      out[(size_t)(t - 1) * NN + nb0 + tid] = acc;
    }

    if (t < TT - 1) {
      produce_X(sm, (t + 1) & 1, nb0, tid);        // X for step t+1
      gb_arrive((unsigned)(t + 1));
      load_x(inputs, nb0, t + 1, tid, xa);         // LSTM(t+1) hidden in the gap
      lstm_cells_x(sm, xa, tid);
      gb_wait((unsigned)(t + 1));
    }
  }
}

extern "C" void kernel_launch(void* const* d_in, const int* in_sizes, int n_in,
                              void* d_out, int out_size, void* d_ws, size_t ws_size,
                              hipStream_t stream) {
  (void)in_sizes; (void)n_in; (void)out_size; (void)d_ws; (void)ws_size;
  const float* inputs = (const float*)d_in[0];
  const float* Ag     = (const float*)d_in[1];
  const float* Wk     = (const float*)d_in[2];
  const float* Wr     = (const float*)d_in[3];
  const float* bls    = (const float*)d_in[4];
  const float* Wgh    = (const float*)d_in[5];
  const float* bgh    = (const float*)d_in[6];
  const float* Wgc    = (const float*)d_in[7];
  const float* bgc    = (const float*)d_in[8];
  const float* Whc    = (const float*)d_in[9];
  const float* Whp    = (const float*)d_in[10];
  const float* bh     = (const float*)d_in[11];
  const float* Wcc    = (const float*)d_in[12];
  const float* Wcp    = (const float*)d_in[13];
  const float* bc     = (const float*)d_in[14];
  const float* Wo     = (const float*)d_in[15];
  const float* bo     = (const float*)d_in[16];
  float* out = (float*)d_out;

  bar_init<<<dim3(1), dim3(NTHR), 0, stream>>>();

  void* args[] = { (void*)&inputs, (void*)&Ag, (void*)&Wk, (void*)&Wr, (void*)&bls,
                   (void*)&Wgh, (void*)&bgh, (void*)&Wgc, (void*)&bgc,
                   (void*)&Whc, (void*)&Whp, (void*)&bh,
                   (void*)&Wcc, (void*)&Wcp, (void*)&bc,
                   (void*)&Wo, (void*)&bo, (void*)&out };
  hipError_t err = hipLaunchCooperativeKernel((void*)gg_kernel, dim3(NBLK), dim3(NTHR),
                                              args, 0, stream);
  if (err != hipSuccess) {
    (void)hipGetLastError();   // clear; fall back (grid 256 <= 256 CUs, 1 block/CU)
    gg_kernel<<<dim3(NBLK), dim3(NTHR), 0, stream>>>(inputs, Ag, Wk, Wr, bls,
                                                     Wgh, bgh, Wgc, bgc,
                                                     Whc, Whp, bh, Wcc, Wcp, bc,
                                                     Wo, bo, out);
  }
}